// Round 1
// baseline (745.044 us; speedup 1.0000x reference)
//
#include <hip/hip_runtime.h>

// ---------------------------------------------------------------------------
// MoE top-2 of 8 experts, SwiGLU. B=2,S=2048 -> T=4096 tokens, H=1024, I=2816.
// Strategy: fp64 gating (selection must match ref), bf16 MFMA grouped GEMMs
// for the experts (only top-2 rows computed: 8192 rows total).
// ---------------------------------------------------------------------------

namespace {
constexpr int TOKS = 4096;
constexpr int HDIM = 1024;
constexpr int IDIM = 2816;
constexpr int NEXP = 8;
constexpr int NROW = 8192;  // TOKS * 2 assignments

// workspace layout (bytes)
constexpr size_t WGT_OFF = 0;                         // bf16 Wg^T  [E][I][H]
constexpr size_t WUT_OFF = 46137344;                  // bf16 Wu^T  [E][I][H]
constexpr size_t WDT_OFF = 92274688;                  // bf16 Wd^T  [E][H][I]
constexpr size_t A_OFF   = 138412032;                 // bf16 A     [8192][H]
constexpr size_t ACT_OFF = 155189248;                 // bf16 act   [8192][I]
constexpr size_t CNT_OFF = 201326592;                 // int[8]
constexpr size_t OFS_OFF = CNT_OFF + 64;              // int[8]
constexpr size_t CUR_OFF = CNT_OFF + 128;             // int[8]
constexpr size_t TIX_OFF = CNT_OFF + 1024;            // int2[4096]
constexpr size_t TPR_OFF = TIX_OFF + 32768;           // float2[4096]
constexpr size_t SLT_OFF = TPR_OFF + 32768;           // int[8192]
// partial fp32 [8192][H] aliases Wg^T region (GEMM1 done before GEMM2 writes)
constexpr size_t PRT_OFF = 0;                         // 33554432 <= 46137344
}  // namespace

typedef __attribute__((ext_vector_type(8))) short short8;
typedef __attribute__((ext_vector_type(4))) float f32x4;

__device__ __forceinline__ unsigned short f2bf(float f) {
  union { float f; unsigned int u; } v; v.f = f;
  unsigned int u = v.u;
  return (unsigned short)((u + 0x7fffu + ((u >> 16) & 1u)) >> 16);  // RNE
}

__device__ __forceinline__ void gl2lds16(const void* g, void* l) {
  __builtin_amdgcn_global_load_lds(
      (const __attribute__((address_space(1))) void*)g,
      (__attribute__((address_space(3))) void*)l, 16, 0, 0);
}

// --------------------------- tiny init ------------------------------------
__global__ void k_init(int* __restrict__ cnt) {
  if (threadIdx.x < NEXP) cnt[threadIdx.x] = 0;
}

// ------------------- fp32 [R][C] -> bf16 [C][R] transpose ------------------
__global__ __launch_bounds__(256) void k_transpose(
    const float* __restrict__ in, unsigned short* __restrict__ out,
    int R, int C) {
  const size_t eoff = (size_t)blockIdx.z * R * C;
  in += eoff; out += eoff;
  __shared__ float tile[64][65];
  const int c0 = blockIdx.x * 64, r0 = blockIdx.y * 64;
  const int tx = threadIdx.x & 63, ty = threadIdx.x >> 6;
#pragma unroll
  for (int i = 0; i < 16; ++i) {
    int r = ty * 16 + i;
    tile[r][tx] = in[(size_t)(r0 + r) * C + c0 + tx];
  }
  __syncthreads();
#pragma unroll
  for (int i = 0; i < 16; ++i) {
    int c = ty * 16 + i;
    out[(size_t)(c0 + c) * R + r0 + tx] = f2bf(tile[tx][c]);
  }
}

// ------------------------------- gating ------------------------------------
__global__ __launch_bounds__(256) void k_gating(
    const float* __restrict__ x, const float* __restrict__ gw,
    float* __restrict__ logits_out, int* __restrict__ cnt,
    int2* __restrict__ tidx, float2* __restrict__ tprb) {
  const int lane = threadIdx.x & 63;
  const int t = blockIdx.x * 4 + (threadIdx.x >> 6);
  const float* xr = x + (size_t)t * HDIM;
  double acc[8];
#pragma unroll
  for (int e = 0; e < 8; ++e) acc[e] = 0.0;
#pragma unroll
  for (int j = 0; j < 16; ++j) {
    int h = lane + j * 64;
    float xv = xr[h];
    const float4* g = (const float4*)(gw + (size_t)h * 8);
    float4 g0 = g[0], g1 = g[1];
    acc[0] += (double)xv * g0.x; acc[1] += (double)xv * g0.y;
    acc[2] += (double)xv * g0.z; acc[3] += (double)xv * g0.w;
    acc[4] += (double)xv * g1.x; acc[5] += (double)xv * g1.y;
    acc[6] += (double)xv * g1.z; acc[7] += (double)xv * g1.w;
  }
#pragma unroll
  for (int off = 32; off > 0; off >>= 1) {
#pragma unroll
    for (int e = 0; e < 8; ++e) acc[e] += __shfl_down(acc[e], off);
  }
  if (lane == 0) {
    float lg[8];
#pragma unroll
    for (int e = 0; e < 8; ++e) lg[e] = (float)acc[e];
#pragma unroll
    for (int e = 0; e < 8; ++e) logits_out[(size_t)t * 8 + e] = lg[e];
    // top-2, lower index wins ties (strict >) to match lax.top_k
    float v0 = lg[0]; int i0 = 0; float v1 = -3.0e38f; int i1 = 0;
#pragma unroll
    for (int e = 1; e < 8; ++e) {
      if (lg[e] > v0) { v1 = v0; i1 = i0; v0 = lg[e]; i0 = e; }
      else if (lg[e] > v1) { v1 = lg[e]; i1 = e; }
    }
    float ex = expf(v1 - v0);
    float p0 = 1.0f / (1.0f + ex);
    float p1 = ex / (1.0f + ex);
    tidx[t] = make_int2(i0, i1);
    tprb[t] = make_float2(p0, p1);
    atomicAdd(&cnt[i0], 1);
    atomicAdd(&cnt[i1], 1);
  }
}

// --------------------------- prefix scan (tiny) ----------------------------
__global__ void k_prefix(const int* __restrict__ cnt, int* __restrict__ offs,
                         int* __restrict__ cur) {
  if (threadIdx.x == 0) {
    int s = 0;
    for (int e = 0; e < NEXP; ++e) { offs[e] = s; cur[e] = s; s += cnt[e]; }
  }
}

// ------------- bucket-build + gather x rows to compact bf16 A --------------
__global__ __launch_bounds__(256) void k_build(
    const float* __restrict__ x, const int2* __restrict__ tidx,
    int* __restrict__ cur, int* __restrict__ slot_row,
    unsigned short* __restrict__ A) {
  const int t = blockIdx.x;
  __shared__ int rs[2];
  if (threadIdx.x == 0) {
    int2 ii = tidx[t];
    int r0 = atomicAdd(&cur[ii.x], 1);
    int r1 = atomicAdd(&cur[ii.y], 1);
    rs[0] = r0; rs[1] = r1;
    slot_row[t * 2] = r0; slot_row[t * 2 + 1] = r1;
  }
  __syncthreads();
  const int r0 = rs[0], r1 = rs[1];
  float4 v = ((const float4*)(x + (size_t)t * HDIM))[threadIdx.x];
  ushort4 b;
  b.x = f2bf(v.x); b.y = f2bf(v.y); b.z = f2bf(v.z); b.w = f2bf(v.w);
  ((ushort4*)(A + (size_t)r0 * HDIM))[threadIdx.x] = b;
  ((ushort4*)(A + (size_t)r1 * HDIM))[threadIdx.x] = b;
}

// ---------------- GEMM1: act = silu(A*Wg^T) * (A*Wu^T)  (bf16) -------------
// block tile: 128(M) x 64(N of I), dual accumulators, BK=64, 16x16x32 MFMA.
__global__ __launch_bounds__(256, 2) void k_gemm1(
    const unsigned short* __restrict__ A, const unsigned short* __restrict__ WgT,
    const unsigned short* __restrict__ WuT, unsigned short* __restrict__ act,
    const int* __restrict__ cnt, const int* __restrict__ offs) {
  const int e = blockIdx.z;
  const int ne = cnt[e];
  const int m0 = blockIdx.y * 128;
  if (m0 >= ne) return;
  const int off = offs[e];
  const int n0 = blockIdx.x * 64;
  const unsigned short* Bg = WgT + ((size_t)e * IDIM + n0) * HDIM;
  const unsigned short* Bu = WuT + ((size_t)e * IDIM + n0) * HDIM;

  __shared__ unsigned short As[128 * 64];
  __shared__ unsigned short Bgs[64 * 64];
  __shared__ unsigned short Bus[64 * 64];

  const int tid = threadIdx.x, w = tid >> 6, lane = tid & 63;
  const int lrow8 = lane >> 3;            // 0..7 rows per 1KB chunk
  const int lcol = (lane & 7) * 8;        // element offset in row

  f32x4 accg[2][4], accu[2][4];
#pragma unroll
  for (int mi = 0; mi < 2; ++mi)
#pragma unroll
    for (int ni = 0; ni < 4; ++ni) {
      accg[mi][ni] = (f32x4){0.f, 0.f, 0.f, 0.f};
      accu[mi][ni] = (f32x4){0.f, 0.f, 0.f, 0.f};
    }

  for (int kt = 0; kt < HDIM / 64; ++kt) {
    const int k0 = kt * 64;
    // stage A: 128 rows x 64 bf16; each wave 4 x 1KB
#pragma unroll
    for (int i = 0; i < 4; ++i) {
      int rl = w * 32 + i * 8 + lrow8;
      int gr = off + m0 + rl;
      gr = gr > (NROW - 1) ? (NROW - 1) : gr;
      gl2lds16(A + (size_t)gr * HDIM + k0 + lcol, &As[(w * 32 + i * 8) * 64]);
    }
    // stage Bg/Bu: 64 rows x 64 bf16 each; each wave 2 x 1KB per matrix
#pragma unroll
    for (int i = 0; i < 2; ++i) {
      int rl = w * 16 + i * 8 + lrow8;
      gl2lds16(Bg + (size_t)rl * HDIM + k0 + lcol, &Bgs[(w * 16 + i * 8) * 64]);
      gl2lds16(Bu + (size_t)rl * HDIM + k0 + lcol, &Bus[(w * 16 + i * 8) * 64]);
    }
    __syncthreads();
#pragma unroll
    for (int kk = 0; kk < 2; ++kk) {
      const int kof = kk * 32 + (lane >> 4) * 8;
      short8 af[2], bgf[4], buf[4];
#pragma unroll
      for (int mi = 0; mi < 2; ++mi)
        af[mi] = *(const short8*)&As[(w * 32 + mi * 16 + (lane & 15)) * 64 + kof];
#pragma unroll
      for (int ni = 0; ni < 4; ++ni) {
        bgf[ni] = *(const short8*)&Bgs[(ni * 16 + (lane & 15)) * 64 + kof];
        buf[ni] = *(const short8*)&Bus[(ni * 16 + (lane & 15)) * 64 + kof];
      }
#pragma unroll
      for (int mi = 0; mi < 2; ++mi)
#pragma unroll
        for (int ni = 0; ni < 4; ++ni) {
          accg[mi][ni] = __builtin_amdgcn_mfma_f32_16x16x32_bf16(
              af[mi], bgf[ni], accg[mi][ni], 0, 0, 0);
          accu[mi][ni] = __builtin_amdgcn_mfma_f32_16x16x32_bf16(
              af[mi], buf[ni], accu[mi][ni], 0, 0, 0);
        }
    }
    __syncthreads();
  }
  // epilogue: silu(g)*u -> bf16
#pragma unroll
  for (int mi = 0; mi < 2; ++mi)
#pragma unroll
    for (int ni = 0; ni < 4; ++ni)
#pragma unroll
      for (int r = 0; r < 4; ++r) {
        int ml = w * 32 + mi * 16 + (lane >> 4) * 4 + r;
        if (m0 + ml < ne) {
          float g = accg[mi][ni][r];
          float u = accu[mi][ni][r];
          float s = g / (1.0f + __expf(-g));
          act[(size_t)(off + m0 + ml) * IDIM + n0 + ni * 16 + (lane & 15)] =
              f2bf(s * u);
        }
      }
}

// ---------------- GEMM2: partial = act * Wd^T  (bf16 -> fp32) --------------
// m97-style: 128x128 tile, 4 waves in 2x2, BK=64.
__global__ __launch_bounds__(256, 2) void k_gemm2(
    const unsigned short* __restrict__ act, const unsigned short* __restrict__ WdT,
    float* __restrict__ partial, const int* __restrict__ cnt,
    const int* __restrict__ offs) {
  const int e = blockIdx.z;
  const int ne = cnt[e];
  const int m0 = blockIdx.y * 128;
  if (m0 >= ne) return;
  const int off = offs[e];
  const int n0 = blockIdx.x * 128;
  const unsigned short* B = WdT + ((size_t)e * HDIM + n0) * IDIM;

  __shared__ unsigned short As[128 * 64];
  __shared__ unsigned short Bs[128 * 64];

  const int tid = threadIdx.x, w = tid >> 6, lane = tid & 63;
  const int lrow8 = lane >> 3;
  const int lcol = (lane & 7) * 8;
  const int wm = (w >> 1) * 64, wn = (w & 1) * 64;

  f32x4 acc[4][4];
#pragma unroll
  for (int mi = 0; mi < 4; ++mi)
#pragma unroll
    for (int ni = 0; ni < 4; ++ni) acc[mi][ni] = (f32x4){0.f, 0.f, 0.f, 0.f};

  for (int kt = 0; kt < IDIM / 64; ++kt) {
    const int k0 = kt * 64;
#pragma unroll
    for (int i = 0; i < 4; ++i) {
      int rl = w * 32 + i * 8 + lrow8;
      int gr = off + m0 + rl;
      gr = gr > (NROW - 1) ? (NROW - 1) : gr;
      gl2lds16(act + (size_t)gr * IDIM + k0 + lcol, &As[(w * 32 + i * 8) * 64]);
      gl2lds16(B + (size_t)rl * IDIM + k0 + lcol, &Bs[(w * 32 + i * 8) * 64]);
    }
    __syncthreads();
#pragma unroll
    for (int kk = 0; kk < 2; ++kk) {
      const int kof = kk * 32 + (lane >> 4) * 8;
      short8 af[4], bf[4];
#pragma unroll
      for (int mi = 0; mi < 4; ++mi)
        af[mi] = *(const short8*)&As[(wm + mi * 16 + (lane & 15)) * 64 + kof];
#pragma unroll
      for (int ni = 0; ni < 4; ++ni)
        bf[ni] = *(const short8*)&Bs[(wn + ni * 16 + (lane & 15)) * 64 + kof];
#pragma unroll
      for (int mi = 0; mi < 4; ++mi)
#pragma unroll
        for (int ni = 0; ni < 4; ++ni)
          acc[mi][ni] = __builtin_amdgcn_mfma_f32_16x16x32_bf16(
              af[mi], bf[ni], acc[mi][ni], 0, 0, 0);
    }
    __syncthreads();
  }
#pragma unroll
  for (int mi = 0; mi < 4; ++mi)
#pragma unroll
    for (int ni = 0; ni < 4; ++ni)
#pragma unroll
      for (int r = 0; r < 4; ++r) {
        int ml = wm + mi * 16 + (lane >> 4) * 4 + r;
        if (m0 + ml < ne)
          partial[(size_t)(off + m0 + ml) * HDIM + n0 + wn + ni * 16 + (lane & 15)] =
              acc[mi][ni][r];
      }
}

// ------------------- combine: out = p0*row0 + p1*row1 ----------------------
__global__ __launch_bounds__(256) void k_combine(
    const float* __restrict__ partial, const int* __restrict__ slot_row,
    const float2* __restrict__ tprb, float* __restrict__ out) {
  const int t = blockIdx.x;
  const int r0 = slot_row[2 * t], r1 = slot_row[2 * t + 1];
  const float2 p = tprb[t];
  float4 a = ((const float4*)(partial + (size_t)r0 * HDIM))[threadIdx.x];
  float4 b = ((const float4*)(partial + (size_t)r1 * HDIM))[threadIdx.x];
  float4 o;
  o.x = p.x * a.x + p.y * b.x;
  o.y = p.x * a.y + p.y * b.y;
  o.z = p.x * a.z + p.y * b.z;
  o.w = p.x * a.w + p.y * b.w;
  ((float4*)(out + (size_t)t * HDIM))[threadIdx.x] = o;
}

// ---------------------------------------------------------------------------
extern "C" void kernel_launch(void* const* d_in, const int* in_sizes, int n_in,
                              void* d_out, int out_size, void* d_ws, size_t ws_size,
                              hipStream_t stream) {
  const float* x  = (const float*)d_in[0];
  const float* gw = (const float*)d_in[1];
  const float* Wg = (const float*)d_in[2];
  const float* Wu = (const float*)d_in[3];
  const float* Wd = (const float*)d_in[4];
  float* out = (float*)d_out;
  char* ws = (char*)d_ws;

  unsigned short* WgT = (unsigned short*)(ws + WGT_OFF);
  unsigned short* WuT = (unsigned short*)(ws + WUT_OFF);
  unsigned short* WdT = (unsigned short*)(ws + WDT_OFF);
  unsigned short* A   = (unsigned short*)(ws + A_OFF);
  unsigned short* act = (unsigned short*)(ws + ACT_OFF);
  float* partial = (float*)(ws + PRT_OFF);
  int* cnt  = (int*)(ws + CNT_OFF);
  int* offs = (int*)(ws + OFS_OFF);
  int* cur  = (int*)(ws + CUR_OFF);
  int2* tidx = (int2*)(ws + TIX_OFF);
  float2* tprb = (float2*)(ws + TPR_OFF);
  int* slot_row = (int*)(ws + SLT_OFF);

  float* logits_out = out + (size_t)TOKS * HDIM;  // output 1 region

  k_init<<<1, 64, 0, stream>>>(cnt);
  // Wg,Wu: [H][I] -> [I][H]; Wd: [I][H] -> [H][I]
  k_transpose<<<dim3(IDIM / 64, HDIM / 64, NEXP), 256, 0, stream>>>(Wg, WgT, HDIM, IDIM);
  k_transpose<<<dim3(IDIM / 64, HDIM / 64, NEXP), 256, 0, stream>>>(Wu, WuT, HDIM, IDIM);
  k_transpose<<<dim3(HDIM / 64, IDIM / 64, NEXP), 256, 0, stream>>>(Wd, WdT, IDIM, HDIM);
  k_gating<<<TOKS / 4, 256, 0, stream>>>(x, gw, logits_out, cnt, tidx, tprb);
  k_prefix<<<1, 64, 0, stream>>>(cnt, offs, cur);
  k_build<<<TOKS, 256, 0, stream>>>(x, tidx, cur, slot_row, A);
  k_gemm1<<<dim3(IDIM / 64, TOKS / 128, NEXP), 256, 0, stream>>>(A, WgT, WuT, act, cnt, offs);
  k_gemm2<<<dim3(HDIM / 128, TOKS / 128, NEXP), 256, 0, stream>>>(act, WdT, partial, cnt, offs);
  k_combine<<<TOKS, 256, 0, stream>>>(partial, slot_row, tprb, out);
}